// Round 11
// baseline (460.394 us; speedup 1.0000x reference)
//
#include <hip/hip_runtime.h>
#include <hip/hip_bf16.h>
#include <cmath>
#include <stdint.h>

typedef __hip_bfloat16 bf16;
typedef __attribute__((ext_vector_type(8))) __bf16 bf16x8;
typedef __attribute__((ext_vector_type(8))) unsigned short u16x8;
typedef __attribute__((ext_vector_type(4))) float f32x4;

// Async global->LDS DMA, 16B per lane. LDS dest must be wave-uniform base;
// HW adds lane*16.
__device__ __forceinline__ void gld16(const void* g, const void* l)
{
    __builtin_amdgcn_global_load_lds(
        (const __attribute__((address_space(1))) unsigned int*)(unsigned long long)g,
        (__attribute__((address_space(3))) unsigned int*)(unsigned int)(unsigned long long)l,
        16, 0, 0);
}

// ---------------------------------------------------------------------------
// Fused fp32 -> bf16 conversion of all 12 tensors in one launch.
// R8 (verified): LN1 fused for segments 0-3 (the x tensor).
// ---------------------------------------------------------------------------
struct CvtSrcs { const float* p[24]; };

__global__ __launch_bounds__(256) void cvt_all(
    CvtSrcs s, bf16* __restrict__ dst,
    const float* __restrict__ lg, const float* __restrict__ lb,
    bf16* __restrict__ lnout)
{
    const int t = threadIdx.x;
    const int i = (blockIdx.x * 256 + t) * 8;
    const int seg = i >> 20;
    const float* sp = s.p[seg] + (i & 1048575);
    const float4 a = *(const float4*)(sp);
    const float4 b = *(const float4*)(sp + 4);
    const float v[8] = {a.x, a.y, a.z, a.w, b.x, b.y, b.z, b.w};
    bf16 tmp[8];
#pragma unroll
    for (int j = 0; j < 8; ++j) tmp[j] = __float2bfloat16(v[j]);
    *(uint4*)(dst + i) = *(const uint4*)tmp;

    if (seg < 4) {   // x tensor: fused LayerNorm (seg uniform per block)
        float s1 = 0.f, s2 = 0.f;
#pragma unroll
        for (int j = 0; j < 8; ++j) { s1 += v[j]; s2 += v[j] * v[j]; }
#pragma unroll
        for (int off = 32; off > 0; off >>= 1) {
            s1 += __shfl_xor(s1, off, 64);
            s2 += __shfl_xor(s2, off, 64);
        }
        __shared__ float r1[4], r2[4];
        const int w = t >> 6;
        if ((t & 63) == 0) { r1[w] = s1; r2[w] = s2; }
        __syncthreads();
        const int rw = (w >> 1) * 2;        // first wave of this row
        s1 = r1[rw] + r1[rw + 1];
        s2 = r2[rw] + r2[rw + 1];
        const float mean = s1 * (1.f / 1024.f);
        const float var  = s2 * (1.f / 1024.f) - mean * mean;
        const float rstd = rsqrtf(var + 1e-5f);
        bf16 lt[8];
        const int c0 = i & 1023;
#pragma unroll
        for (int j = 0; j < 8; ++j)
            lt[j] = __float2bfloat16((v[j] - mean) * rstd * lg[c0 + j] + lb[c0 + j]);
        *(uint4*)(lnout + i) = *(const uint4*)lt;
    }
}

enum {
    EPI_QSCALE = 0,          // out_bf16 = (C + bias) * 0.125
    EPI_KV = 1,              // N=2048 fused: K plain / Vt transposed
    EPI_RELU = 2,            // out_bf16 = relu(C + bias)
    EPI_RES_F32_F32OUT = 3,  // out_f32  = res_f32 + C + bias
    EPI_PART = 4             // (unused since R8)
};

// ---------------------------------------------------------------------------
// gemm256: C[4096,N] = A[4096,K] @ W[N,K]^T (+bias). 256x256 tile, BK=64,
// 512 thr = 8 waves (2M x 4N), per-wave 128x64 out.
// R10 K-loop: faithful m201 phase discipline — EVERY 16-MFMA cluster is
// {reads+stage -> s_barrier -> lgkmcnt(0) -> setprio MFMA -> s_barrier}
// (8 barriers/K-tile). Counted vmcnt certify-before-barrier:
//   P0: after staging, vmcnt(2) completes a1,a3 of tile tt (4 outstanding);
//       barrier publishes -> P1's reads safe.
//   P3: after staging, vmcnt(2) completes oldest 6 of tile tt+1 (8 out);
//       barrier publishes -> next P0's reads safe.
//   Never drains to 0 mid-loop; final tile vmcnt(0) at entry (2 out).
// Staging/XOR-swizzle (R2, 0 conflicts) and LDS-bounce epilogue (R5)
// unchanged. Used for FFN1.
// ---------------------------------------------------------------------------
template <int EPI>
__global__ __launch_bounds__(512, 2) void gemm256(
    const bf16* __restrict__ A, const bf16* __restrict__ W,
    const float* __restrict__ bias, void* __restrict__ out,
    int N, int Kiter, int Kstride)
{
    __shared__ __align__(16) unsigned short sA[2][2][128 * 64];  // [slot][half]
    __shared__ __align__(16) unsigned short sB[2][2][128 * 64];

    const int t  = threadIdx.x;          // 0..511
    const int l  = t & 63;
    const int w  = t >> 6;               // 0..7
    const int wv = w * 64;
    const int wr = w >> 2;               // 0..1 : M-half of block
    const int wc = w & 3;                // 0..3 : N-quarter of block
    const int lm = l & 15;
    const int kq = l >> 4;
    const int rx = lm & 7;               // read-side swizzle row bits

    int bx = blockIdx.x;
    // XCD-aware: xcd owns 2 contiguous bm-bands; bm iterates fastest.
    const int xcd = bx & 7;
    const int ib  = bx >> 3;
    const int bm  = xcd * 2 + (ib & 1);
    const int bn  = ib >> 1;

    const bf16* gA = A + (size_t)(bm * 256 + (t >> 3)) * Kstride
                       + ((t & 7) ^ ((t >> 3) & 7)) * 8;
    const bf16* gB = W + (size_t)(bn * 256 + (t >> 3)) * Kstride
                       + ((t & 7) ^ ((t >> 3) & 7)) * 8;

#define SQA(slot, kt, j)                                        \
    gld16(gA + (size_t)((j) * 64) * Kstride + (kt) * 64,        \
          &sA[slot][(j) >> 1][(((j) & 1) * 512 + wv) * 8])
#define SQB(slot, kt, j)                                        \
    gld16(gB + (size_t)((j) * 64) * Kstride + (kt) * 64,        \
          &sB[slot][(j) >> 1][(((j) & 1) * 512 + wv) * 8])

    bf16x8 af[4][2], bg[2][2];

#define READ_AF(s_, mh)                                                     \
    do {                                                                    \
        _Pragma("unroll")                                                   \
        for (int mi = 0; mi < 4; ++mi)                                      \
            _Pragma("unroll")                                               \
            for (int kk = 0; kk < 2; ++kk) {                                \
                const int lr = (mh) * 64 + mi * 16 + lm;                    \
                const int sl = ((kk << 2) | kq) ^ rx;                       \
                af[mi][kk] = __builtin_bit_cast(bf16x8,                     \
                    *(const u16x8*)(&sA[s_][wr][lr * 64 + sl * 8]));        \
            }                                                               \
    } while (0)
#define READ_BG(s_, nh)                                                     \
    do {                                                                    \
        _Pragma("unroll")                                                   \
        for (int ni = 0; ni < 2; ++ni)                                      \
            _Pragma("unroll")                                               \
            for (int kk = 0; kk < 2; ++kk) {                                \
                const int lr = (wc & 1) * 64 + (nh) * 32 + ni * 16 + lm;    \
                const int sl = ((kk << 2) | kq) ^ rx;                       \
                bg[ni][kk] = __builtin_bit_cast(bf16x8,                     \
                    *(const u16x8*)(&sB[s_][wc >> 1][lr * 64 + sl * 8]));   \
            }                                                               \
    } while (0)
#define MFMA_QUAD(mh, nh)                                                   \
    do {                                                                    \
        __builtin_amdgcn_s_setprio(1);                                      \
        _Pragma("unroll")                                                   \
        for (int mi = 0; mi < 4; ++mi)                                      \
            _Pragma("unroll")                                               \
            for (int ni = 0; ni < 2; ++ni)                                  \
                _Pragma("unroll")                                           \
                for (int kk = 0; kk < 2; ++kk)                              \
                    acc[(mh) * 4 + mi][(nh) * 2 + ni] =                     \
                        __builtin_amdgcn_mfma_f32_16x16x32_bf16(            \
                            af[mi][kk], bg[ni][kk],                         \
                            acc[(mh) * 4 + mi][(nh) * 2 + ni], 0, 0, 0);    \
        __builtin_amdgcn_s_setprio(0);                                      \
    } while (0)
#define BARRIER() do { __builtin_amdgcn_s_barrier();                        \
                       __builtin_amdgcn_sched_barrier(0); } while (0)
#define LGKM0() do { asm volatile("s_waitcnt lgkmcnt(0)" ::: "memory");     \
                     __builtin_amdgcn_sched_barrier(0); } while (0)
#define WAITV2() asm volatile("s_waitcnt vmcnt(2)" ::: "memory")
#define WAITV0() asm volatile("s_waitcnt vmcnt(0)" ::: "memory")

    f32x4 acc[8][4] = {};
    const int NT = Kiter >> 6;

    // prologue: tile 0 -> slot 0; issue order b0 b1 b2 b3 a0 a2 a1 a3.
    SQB(0, 0, 0); SQB(0, 0, 1); SQB(0, 0, 2); SQB(0, 0, 3);
    SQA(0, 0, 0); SQA(0, 0, 2); SQA(0, 0, 1); SQA(0, 0, 3);
    WAITV2();
    __syncthreads();

    for (int tt = 0; tt < NT - 1; ++tt) {
        const int s = tt & 1, d = s ^ 1, kn = tt + 1;
        // P0 (mh0,nh0): reads certified; stage b0',b1'; certify a1,a3
        READ_AF(s, 0); READ_BG(s, 0);
        SQB(d, kn, 0); SQB(d, kn, 1);
        WAITV2();                 // 4 outstanding -> completes a1,a3
        BARRIER(); LGKM0();
        MFMA_QUAD(0, 0);
        BARRIER();
        // P1 (mh1,nh0): reads a1,a3 (certified at P0)
        READ_AF(s, 1);
        SQB(d, kn, 2); SQB(d, kn, 3);
        BARRIER(); LGKM0();
        MFMA_QUAD(1, 0);
        BARRIER();
        // P2 (mh1,nh1)
        READ_BG(s, 1);
        SQA(d, kn, 0); SQA(d, kn, 2);
        BARRIER(); LGKM0();
        MFMA_QUAD(1, 1);
        BARRIER();
        // P3 (mh0,nh1): stage a1',a3'; certify next tile's oldest 6
        READ_AF(s, 0);
        SQA(d, kn, 1); SQA(d, kn, 3);
        WAITV2();                 // 8 outstanding -> completes b0'..b3',a0',a2'
        BARRIER(); LGKM0();
        MFMA_QUAD(0, 1);
        BARRIER();
    }
    {   // final tile: 2 outstanding (a1,a3) -> drain at entry; no staging
        const int s = (NT - 1) & 1;
        READ_AF(s, 0); READ_BG(s, 0);
        WAITV0();
        BARRIER(); LGKM0();
        MFMA_QUAD(0, 0);
        BARRIER();
        READ_AF(s, 1);
        MFMA_QUAD(1, 0);
        READ_BG(s, 1);
        MFMA_QUAD(1, 1);
        READ_AF(s, 0);
        MFMA_QUAD(0, 1);
    }

    // ---- Epilogue (R5): LDS-bounce vectorized store ----
    __syncthreads();
    unsigned short* scr = (w < 4) ? &sA[0][0][0] + w * 8192
                                  : &sB[0][0][0] + (w - 4) * 8192;

#pragma unroll
    for (int NI = 0; NI < 4; ++NI) {
        const int col = bn * 256 + wc * 64 + NI * 16 + lm;
        const float bv = bias[col];
        const int c  = NI * 2 + (lm >> 3);
        const int ci = lm & 7;
#pragma unroll
        for (int MI = 0; MI < 8; ++MI) {
#pragma unroll
            for (int r = 0; r < 4; ++r) {
                float v = acc[MI][NI][r] + bv;
                if (EPI == EPI_RELU) v = fmaxf(v, 0.f);
                const int row = MI * 16 + kq * 4 + r;
                scr[row * 64 + ((c ^ (row & 7)) * 8) + ci] =
                    __builtin_bit_cast(unsigned short, (__bf16)v);
            }
        }
    }
#pragma unroll
    for (int it = 0; it < 16; ++it) {
        const int row = it * 8 + (l >> 3);
        const int lc  = l & 7;
        const u16x8 vv = *(const u16x8*)&scr[row * 64 + ((lc ^ (row & 7)) * 8)];
        const int Crow = bm * 256 + wr * 128 + row;
        const int Ccol = bn * 256 + wc * 64 + lc * 8;
        *(u16x8*)((bf16*)out + (size_t)Crow * N + Ccol) = vv;
    }
#undef SQA
#undef SQB
#undef READ_AF
#undef READ_BG
#undef MFMA_QUAD
#undef BARRIER
#undef LGKM0
#undef WAITV2
#undef WAITV0
}

// ---------------------------------------------------------------------------
// gemm_bt body (R9-verified schedule): 128x64 tile, BK=64, 4 waves (2M x 2N),
// wave-tile 64x32, LDS 48KB, counted-vmcnt 4-phase. Shared arrays passed in
// so the body can be reused by the fused QKV kernel (one LDS allocation).
// ---------------------------------------------------------------------------
template <int EPI>
__device__ __forceinline__ void gemm_bt_body(
    unsigned short* __restrict__ sAp, unsigned short* __restrict__ sBp,
    const bf16* __restrict__ A, const bf16* __restrict__ W,
    const float* __restrict__ bias, const float* __restrict__ bias2,
    const float* __restrict__ res, void* __restrict__ out,
    int N, int Kiter, int Kstride, int bx)
{
    const int t  = threadIdx.x;     // 0..255
    const int l  = t & 63;
    const int w  = t >> 6;          // 0..3
    const int wv = w * 64;
    const int wr = w >> 1;          // 0..1 : M-half (64 rows)
    const int wc = w & 1;           // 0..1 : N-half (32 cols)
    const int lm = l & 15;
    const int kq = l >> 4;
    const int rx = lm & 7;

    const int xcd = bx & 7;
    const int ib  = bx >> 3;
    const int bm  = xcd * 4 + (ib & 3);   // 32 bm tiles, 4 per XCD
    const int bn  = ib >> 2;

    const bf16* gA = A + (size_t)(bm * 128 + (t >> 3)) * Kstride
                       + ((t & 7) ^ ((t >> 3) & 7)) * 8;
    const bf16* gB = W + (size_t)(bn * 64 + (t >> 3)) * Kstride
                       + ((t & 7) ^ ((t >> 3) & 7)) * 8;

#define SQA_B(slot, kt, j)                                      \
    gld16(gA + (size_t)((j) * 32) * Kstride + (kt) * 64,        \
          sAp + (slot) * 8192 + ((j) * 256 + wv) * 8)
#define SQB_B(slot, kt, j)                                      \
    gld16(gB + (size_t)((j) * 32) * Kstride + (kt) * 64,        \
          sBp + (slot) * 4096 + ((j) * 256 + wv) * 8)

    bf16x8 af[4][2], bg[2][2];

#define READ_A_B(s_, mh, kk)                                                \
    do {                                                                    \
        _Pragma("unroll")                                                   \
        for (int m2 = 0; m2 < 2; ++m2) {                                    \
            const int mi = (mh) * 2 + m2;                                   \
            const int lr = wr * 64 + mi * 16 + lm;                          \
            const int sl = (((kk) << 2) | kq) ^ rx;                         \
            af[mi][kk] = __builtin_bit_cast(bf16x8,                         \
                *(const u16x8*)(sAp + (s_) * 8192 + lr * 64 + sl * 8));     \
        }                                                                   \
    } while (0)
#define READ_B_B(s_, kk)                                                    \
    do {                                                                    \
        _Pragma("unroll")                                                   \
        for (int ni = 0; ni < 2; ++ni) {                                    \
            const int lr = wc * 32 + ni * 16 + lm;                          \
            const int sl = (((kk) << 2) | kq) ^ rx;                         \
            bg[ni][kk] = __builtin_bit_cast(bf16x8,                         \
                *(const u16x8*)(sBp + (s_) * 4096 + lr * 64 + sl * 8));     \
        }                                                                   \
    } while (0)
#define MFMA_PH_B(mh, kk)                                                   \
    do {                                                                    \
        __builtin_amdgcn_s_setprio(1);                                      \
        _Pragma("unroll")                                                   \
        for (int m2 = 0; m2 < 2; ++m2)                                      \
            _Pragma("unroll")                                               \
            for (int ni = 0; ni < 2; ++ni)                                  \
                acc[(mh) * 2 + m2][ni] =                                    \
                    __builtin_amdgcn_mfma_f32_16x16x32_bf16(                \
                        af[(mh) * 2 + m2][kk], bg[ni][kk],                  \
                        acc[(mh) * 2 + m2][ni], 0, 0, 0);                   \
        __builtin_amdgcn_s_setprio(0);                                      \
    } while (0)
#define BARRIER_B() do { __builtin_amdgcn_s_barrier();                      \
                         __builtin_amdgcn_sched_barrier(0); } while (0)
#define WAITV2_B() asm volatile("s_waitcnt vmcnt(2)" ::: "memory")
#define WAITV0_B() asm volatile("s_waitcnt vmcnt(0)" ::: "memory")

    f32x4 acc[4][2] = {};
    const int NT = Kiter >> 6;

    // prologue: tile 0 -> slot 0; order b0 b1 a0 a2 a1 a3
    SQB_B(0, 0, 0); SQB_B(0, 0, 1);
    SQA_B(0, 0, 0); SQA_B(0, 0, 2);
    SQA_B(0, 0, 1); SQA_B(0, 0, 3);

    for (int tt = 0; tt < NT - 1; ++tt) {
        const int s = tt & 1, d = s ^ 1, kn = tt + 1;
        // P0 (mh0,kk0): certify b0,b1,a0,a2 of tile tt (6 outstanding)
        WAITV2_B(); BARRIER_B();
        SQB_B(d, kn, 0); SQB_B(d, kn, 1);
        READ_A_B(s, 0, 0); READ_B_B(s, 0);
        MFMA_PH_B(0, 0);
        // P1 (mh1,kk0): certify a1,a3 (4 outstanding)
        WAITV2_B(); BARRIER_B();
        SQA_B(d, kn, 0); SQA_B(d, kn, 2);
        READ_A_B(s, 1, 0);
        MFMA_PH_B(1, 0);
        // P2 (mh1,kk1): wait-free
        SQA_B(d, kn, 1); SQA_B(d, kn, 3);
        READ_A_B(s, 1, 1); READ_B_B(s, 1);
        MFMA_PH_B(1, 1);
        // P3 (mh0,kk1): wait-free
        READ_A_B(s, 0, 1);
        MFMA_PH_B(0, 1);
    }
    {   // final tile: no staging
        const int s = (NT - 1) & 1;
        WAITV2_B(); BARRIER_B();
        READ_A_B(s, 0, 0); READ_B_B(s, 0);
        MFMA_PH_B(0, 0);
        WAITV0_B(); BARRIER_B();
        READ_A_B(s, 1, 0);
        MFMA_PH_B(1, 0);
        READ_A_B(s, 1, 1); READ_B_B(s, 1);
        MFMA_PH_B(1, 1);
        READ_A_B(s, 0, 1);
        MFMA_PH_B(0, 1);
    }
#undef SQA_B
#undef SQB_B
#undef READ_A_B
#undef READ_B_B
#undef MFMA_PH_B
#undef BARRIER_B
#undef WAITV2_B
#undef WAITV0_B

    // Epilogue. C/D: col = lane&15 (+16*ni), row = kq*4 + r (+16*mi).
#pragma unroll
    for (int ni = 0; ni < 2; ++ni) {
        const int col = bn * 64 + wc * 32 + ni * 16 + lm;
        float bv = 0.f;
        if (EPI == EPI_KV) bv = (col < 1024) ? bias[col] : bias2[col - 1024];
        else bv = bias[col];
#pragma unroll
        for (int mi = 0; mi < 4; ++mi) {
#pragma unroll
            for (int r = 0; r < 4; ++r) {
                const int row = bm * 128 + wr * 64 + mi * 16 + kq * 4 + r;
                float v = acc[mi][ni][r] + bv;
                if (EPI == EPI_QSCALE) v *= 0.125f;
                if (EPI == EPI_RELU) v = fmaxf(v, 0.f);
                if (EPI == EPI_KV) {
                    if (col < 1024) {
                        ((bf16*)out)[(size_t)row * 1024 + col] = __float2bfloat16(v);
                    } else {
                        const int ch = col - 1024;  // h*64 + d
                        const size_t idx = (size_t)4 * 1048576 +
                            ((size_t)((row >> 10) * 16 + (ch >> 6)) * 64 + (ch & 63)) * 1024
                            + (row & 1023);
                        ((bf16*)out)[idx] = __float2bfloat16(v);
                    }
                } else if (EPI == EPI_RES_F32_F32OUT) {
                    const size_t idx = (size_t)row * N + col;
                    ((float*)out)[idx] = v + res[idx];
                } else {
                    ((bf16*)out)[(size_t)row * N + col] = __float2bfloat16(v);
                }
            }
        }
    }
}

template <int EPI>
__global__ __launch_bounds__(256, 3) void gemm_bt(
    const bf16* __restrict__ A, const bf16* __restrict__ W,
    const float* __restrict__ bias, const float* __restrict__ bias2,
    const float* __restrict__ res, void* __restrict__ out,
    int M, int N, int Kiter, int Kstride)
{
    __shared__ __align__(16) unsigned short sA[2 * 128 * 64];
    __shared__ __align__(16) unsigned short sB[2 * 64 * 64];
    gemm_bt_body<EPI>(sA, sB, A, W, bias, bias2, res, out,
                      N, Kiter, Kstride, blockIdx.x);
}

// ---------------------------------------------------------------------------
// qkv_fused (R10): QSCALE (512 blocks) + KV (1024 blocks) in one 1536-block
// launch. The two halves are independent (lnbuf vs x/memory) — co-scheduling
// fills the machine and removes a launch gap. Block-range dispatch; local
// bx keeps the XCD swizzle parity (512 is a multiple of 8).
// ---------------------------------------------------------------------------
__global__ __launch_bounds__(256, 3) void qkv_fused(
    const bf16* __restrict__ Aq, const bf16* __restrict__ Wq,
    const float* __restrict__ bq, bf16* __restrict__ Qb,
    const bf16* __restrict__ Akv, const bf16* __restrict__ Wkv,
    const float* __restrict__ bk, const float* __restrict__ bv,
    bf16* __restrict__ Kb)
{
    __shared__ __align__(16) unsigned short sA[2 * 128 * 64];
    __shared__ __align__(16) unsigned short sB[2 * 64 * 64];
    const int bx = blockIdx.x;
    if (bx < 512)
        gemm_bt_body<EPI_QSCALE>(sA, sB, Aq, Wq, bq, nullptr, nullptr, Qb,
                                 1024, 1024, 1024, bx);
    else
        gemm_bt_body<EPI_KV>(sA, sB, Akv, Wkv, bk, bv, nullptr, Kb,
                             2048, 1024, 1024, bx - 512);
}

// ---------------------------------------------------------------------------
// Flash attention (MFMA). R6a/R6b verified: XCD-local remap + swizzled
// conflict-free K/V tiles.
// ---------------------------------------------------------------------------
template <bool CAUSAL, bool SBIAS>
__global__ __launch_bounds__(256, 2) void flash_attn(
    const bf16* __restrict__ Q, const bf16* __restrict__ K,
    const bf16* __restrict__ Vt, bf16* __restrict__ O,
    const float* __restrict__ sbias, const float* __restrict__ scale_ptr)
{
    __shared__ __align__(16) unsigned short sK[2][64 * 64];
    __shared__ __align__(16) unsigned short sV[2][64 * 64];
    __shared__ __align__(16) unsigned short sP[4 * 32 * 72];

    const int t  = threadIdx.x;
    const int l  = t & 63;
    const int w  = t >> 6;
    const int wv = w * 64;
    const int lm = l & 15;
    const int kq = l >> 4;

    const int bh = blockIdx.x & 63;      // same-XCD for all 8 q-blocks of bh
    const int qb = blockIdx.x >> 6;
    const int h  = bh & 15;
    const int b  = bh >> 4;

    const int tb = qb * 128 + w * 32;
    const size_t qrow0 = (size_t)(b * 1024 + tb) * 1024 + h * 64;

    bf16x8 qf[2][2];
#pragma unroll
    for (int mi = 0; mi < 2; ++mi)
#pragma unroll
        for (int kk = 0; kk < 2; ++kk)
            qf[mi][kk] = __builtin_bit_cast(bf16x8,
                *(const u16x8*)(Q + qrow0 + (size_t)(mi * 16 + lm) * 1024 + kk * 32 + kq * 8));

    float cs = 0.f; const float* sb = nullptr;
    if (SBIAS) { cs = scale_ptr[0]; sb = sbias + b * 1024; }

    const bf16* gK = K  + (size_t)(b * 1024 + (t >> 3)) * 1024 + h * 64
                   + ((t & 7) ^ ((t >> 3) & 7)) * 8;
    const bf16* gV = Vt + (size_t)((b * 16 + h) * 64 + (t >> 3)) * 1024
                   + ((t & 7) ^ ((t >> 3) & 7)) * 8;
    __bf16* sPw = (__bf16*)sP + w * 32 * 72;

#define STAGE_KV(buf, s0r)                                                   \
    do {                                                                     \
        gld16(gK + (size_t)(s0r) * 1024,        &sK[buf][wv * 8]);           \
        gld16(gK + (size_t)((s0r) + 32) * 1024, &sK[buf][2048 + wv * 8]);    \
        gld16(gV + (s0r),                       &sV[buf][wv * 8]);           \
        gld16(gV + (s0r) + 32 * 1024,           &sV[buf][2048 + wv * 8]);    \
    } while (0)

    const int niter = CAUSAL ? (2 * qb + 2) : 16;

    STAGE_KV(0, 0);
    __syncthreads();

    f32x4 acc_o[2][4] = {};
    f32x4 l_run[2] = {};

    for (int it = 0; it < niter; ++it) {
        const int s0 = it * 64;
        const int cur = it & 1;

        if (it + 1 < niter) STAGE_KV(cur ^ 1, s0 + 64);

        f32x4 accs[2][4] = {};
#pragma unroll
        for (int ni = 0; ni < 4; ++ni)
#pragma unroll
            for (int kk = 0; kk < 2; ++kk) {
                const bf16x8 kf = __builtin_bit_cast(bf16x8,
                    *(const u16x8*)(&sK[cur][(ni * 16 + lm) * 64
                        + ((((kk << 2) | kq)) ^ (lm & 7)) * 8]));
#pragma unroll
                for (int mi = 0; mi < 2; ++mi)
                    accs[mi][ni] = __builtin_amdgcn_mfma_f32_16x16x32_bf16(
                        qf[mi][kk], kf, accs[mi][ni], 0, 0, 0);
            }

        if (SBIAS) {
#pragma unroll
            for (int ni = 0; ni < 4; ++ni) {
                const float sv = cs * sb[s0 + ni * 16 + lm];
#pragma unroll
                for (int mi = 0; mi < 2; ++mi)
#pragma unroll
                    for (int r = 0; r < 4; ++r) accs[mi][ni][r] += sv;
            }
        }
        if (CAUSAL && (s0 + 63 > tb)) {
#pragma unroll
            for (int ni = 0; ni < 4; ++ni) {
                const int s = s0 + ni * 16 + lm;
#pragma unroll
                for (int mi = 0; mi < 2; ++mi)
#pragma unroll
                    for (int r = 0; r < 4; ++r)
                        if (s > tb + mi * 16 + kq * 4 + r) accs[mi][ni][r] = -1e30f;
            }
        }

#pragma unroll
        for (int mi = 0; mi < 2; ++mi)
#pragma unroll
            for (int ni = 0; ni < 4; ++ni)
#pragma unroll
                for (int r = 0; r < 4; ++r) {
                    const float e = __expf(accs[mi][ni][r]);
                    l_run[mi][r] += e;
                    sPw[(mi * 16 + kq * 4 + r) * 72 + ni * 16 + lm] = (__bf16)e;
                }

#pragma unroll
        for (int kk = 0; kk < 2; ++kk) {
            bf16x8 pf[2];
#pragma unroll
            for (int mi = 0; mi < 2; ++mi)
                pf[mi] = __builtin_bit_cast(bf16x8,
                    *(const u16x8*)(sPw + (mi * 16 + lm) * 72 + kk * 32 + kq * 8));
#pragma unroll
            for (int di = 0; di < 4; ++di) {
                const bf16x8 vf = __builtin_bit_cast(bf16x8,
                    *(const u16x8*)(&sV[cur][(di * 16 + lm) * 64
                        + ((((kk << 2) | kq)) ^ (lm & 7)) * 8]));
#pragma unroll
                for (int mi = 0; mi < 2; ++mi)
                    acc_o[mi][di] = __builtin_amdgcn_mfma_f32_16x16x32_bf16(
                        pf[mi], vf, acc_o[mi][di], 0, 0, 0);
            }
        }

        __syncthreads();
    }
#undef STAGE_KV

#pragma unroll
    for (int mi = 0; mi < 2; ++mi) {
        f32x4 lt = l_run[mi];
#pragma unroll
        for (int x = 1; x < 16; x <<= 1)
#pragma unroll
            for (int r = 0; r < 4; ++r) lt[r] += __shfl_xor(lt[r], x, 64);
#pragma unroll
        for (int r = 0; r < 4; ++r) lt[r] = 1.f / lt[r];
#pragma unroll
        for (int di = 0; di < 4; ++di)
#pragma unroll
            for (int r = 0; r < 4; ++r) {
                const size_t idx = (size_t)(b * 1024 + tb + mi * 16 + kq * 4 + r) * 1024
                                 + h * 64 + di * 16 + lm;
                O[idx] = __float2bfloat16(acc_o[mi][di][r] * lt[r]);
            }
    }
}

// ---------------------------------------------------------------------------
// LayerNorm over D=1024 (fp32 in, bf16 out), one block per row, 4 elems/thr.
// ---------------------------------------------------------------------------
__global__ __launch_bounds__(256) void ln_kernel(
    const float* __restrict__ xin, const float* __restrict__ g,
    const float* __restrict__ bta, bf16* __restrict__ out)
{
    const int row = blockIdx.x;
    const int t = threadIdx.x;
    const size_t base = (size_t)row * 1024 + t * 4;

    const float4 f = *(const float4*)(xin + base);
    const float v[4] = {f.x, f.y, f.z, f.w};
    float s1 = v[0] + v[1] + v[2] + v[3];
    float s2 = v[0]*v[0] + v[1]*v[1] + v[2]*v[2] + v[3]*v[3];
#pragma unroll
    for (int off = 32; off > 0; off >>= 1) {
        s1 += __shfl_xor(s1, off, 64);
        s2 += __shfl_xor(s2, off, 64);
    }
    __shared__ float r1[4], r2[4];
    if ((t & 63) == 0) { r1[t >> 6] = s1; r2[t >> 6] = s2; }
    __syncthreads();
    s1 = r1[0] + r1[1] + r1[2] + r1[3];
    s2 = r2[0] + r2[1] + r2[2] + r2[3];
    const float mean = s1 * (1.f / 1024.f);
    const float var  = s2 * (1.f / 1024.f) - mean * mean;
    const float rstd = rsqrtf(var + 1e-5f);
#pragma unroll
    for (int j = 0; j < 4; ++j) {
        const int c = t * 4 + j;
        out[base + j] = __float2bfloat16((v[j] - mean) * rstd * g[c] + bta[c]);
    }
}

// ---------------------------------------------------------------------------
extern "C" void kernel_launch(void* const* d_in, const int* in_sizes, int n_in,
                              void* d_out, int out_size, void* d_ws, size_t ws_size,
                              hipStream_t stream)
{
    const float* x       = (const float*)d_in[0];
    const float* memory  = (const float*)d_in[1];
    const float* sbias   = (const float*)d_in[2];
    const float* sa_bq = (const float*)d_in[7];
    const float* sa_bk = (const float*)d_in[9];
    const float* sa_bv = (const float*)d_in[11];
    const float* sa_bo = (const float*)d_in[13];
    const float* ca_bq = (const float*)d_in[16];
    const float* ca_bk = (const float*)d_in[18];
    const float* ca_bv = (const float*)d_in[20];
    const float* ca_bo = (const float*)d_in[22];
    const float* ca_scale = (const float*)d_in[23];
    const float* ln1_g = (const float*)d_in[24]; const float* ln1_b = (const float*)d_in[25];
    const float* ln2_g = (const float*)d_in[26]; const float* ln2_b = (const float*)d_in[27];
    const float* ln3_g = (const float*)d_in[28]; const float* ln3_b = (const float*)d_in[29];
    const float* b1 = (const float*)d_in[31];
    const float* b2 = (const float*)d_in[33];

    char* ws = (char*)d_ws;
    const size_t MB = (size_t)1 << 20;
    float* x1    = (float*)(ws + 0 * MB);
    float* x2    = (float*)(ws + 16 * MB);
    bf16* lnbuf  = (bf16*)(ws + 32 * MB);
    bf16* Qb     = (bf16*)(ws + 40 * MB);
    bf16* Kb     = (bf16*)(ws + 48 * MB);
    bf16* Vtb    = (bf16*)(ws + 56 * MB);
    bf16* Ob     = (bf16*)(ws + 64 * MB);
    bf16* ffnmid = (bf16*)(ws + 40 * MB);
    bf16* wx     = (bf16*)(ws + 72 * MB);
    bf16* wmem   = (bf16*)(ws + 80 * MB);
    bf16* bw     = (bf16*)(ws + 88 * MB);
    bf16* b_sa_wq = bw + 0 * 1048576, *b_sa_wk = bw + 1 * 1048576;
    bf16* b_sa_wo = bw + 3 * 1048576;
    bf16* b_ca_wq = bw + 4 * 1048576, *b_ca_wk = bw + 5 * 1048576;
    bf16* b_ca_wo = bw + 7 * 1048576;
    bf16* b_w1   = (bf16*)(ws + 104 * MB);
    bf16* b_w2   = (bf16*)(ws + 112 * MB);

    const int M = 4096;
    dim3 blk256(256), blk512(512);
    const dim3 gQ(512);      // (4096/128)*(1024/64): 128x64 tiles
    const dim3 gQKV(1536);   // fused: 512 QSCALE + 1024 KV
    const dim3 gFA(512);     // 64 (b,h) x 8 q-blocks
    const dim3 g256(256);    // FFN1: 16x16 tiles (256^2)

    CvtSrcs cs;
    for (int c = 0; c < 4; ++c) {
        cs.p[c]      = x + (size_t)c * 1048576;
        cs.p[4 + c]  = memory + (size_t)c * 1048576;
        cs.p[16 + c] = (const float*)d_in[30] + (size_t)c * 1048576;  // w1
        cs.p[20 + c] = (const float*)d_in[32] + (size_t)c * 1048576;  // w2
    }
    cs.p[8]  = (const float*)d_in[6];
    cs.p[9]  = (const float*)d_in[8];
    cs.p[10] = (const float*)d_in[10];
    cs.p[11] = (const float*)d_in[12];
    cs.p[12] = (const float*)d_in[15];
    cs.p[13] = (const float*)d_in[17];
    cs.p[14] = (const float*)d_in[19];
    cs.p[15] = (const float*)d_in[21];
    // cvt + fused LN1 (segments 0-3 = x -> lnbuf)
    cvt_all<<<24 * 1048576 / 2048, blk256, 0, stream>>>(
        cs, wx, ln1_g, ln1_b, lnbuf);

    // ---- self-attention ----
    qkv_fused<<<gQKV, blk256, 0, stream>>>(
        lnbuf, b_sa_wq, sa_bq, Qb, wx, b_sa_wk, sa_bk, sa_bv, Kb);
    flash_attn<true, false><<<gFA, blk256, 0, stream>>>(Qb, Kb, Vtb, Ob, nullptr, nullptr);
    gemm_bt<EPI_RES_F32_F32OUT><<<gQ, blk256, 0, stream>>>(
        Ob, b_sa_wo, sa_bo, nullptr, x, x1, M, 1024, 1024, 1024);

    // ---- cross-attention ----
    ln_kernel<<<4096, blk256, 0, stream>>>(x1, ln2_g, ln2_b, lnbuf);
    qkv_fused<<<gQKV, blk256, 0, stream>>>(
        lnbuf, b_ca_wq, ca_bq, Qb, wmem, b_ca_wk, ca_bk, ca_bv, Kb);
    flash_attn<false, true><<<gFA, blk256, 0, stream>>>(Qb, Kb, Vtb, Ob, sbias, ca_scale);
    gemm_bt<EPI_RES_F32_F32OUT><<<gQ, blk256, 0, stream>>>(
        Ob, b_ca_wo, ca_bo, nullptr, x1, x2, M, 1024, 1024, 1024);

    // ---- FFN ----
    ln_kernel<<<4096, blk256, 0, stream>>>(x2, ln3_g, ln3_b, lnbuf);
    gemm256<EPI_RELU><<<g256, blk512, 0, stream>>>(
        lnbuf, b_w1, b1, ffnmid, 4096, 1024, 1024);
    // FFN2 direct (R8): K=4096, fused residual + bias, fp32 out.
    gemm_bt<EPI_RES_F32_F32OUT><<<gQ, blk256, 0, stream>>>(
        ffnmid, b_w2, b2, nullptr, x2, d_out, M, 1024, 4096, 4096);
}

// Round 12
// 448.615 us; speedup vs baseline: 1.0263x; 1.0263x over previous
//
#include <hip/hip_runtime.h>
#include <hip/hip_bf16.h>
#include <cmath>
#include <stdint.h>

typedef __hip_bfloat16 bf16;
typedef __attribute__((ext_vector_type(8))) __bf16 bf16x8;
typedef __attribute__((ext_vector_type(8))) unsigned short u16x8;
typedef __attribute__((ext_vector_type(4))) float f32x4;

// Async global->LDS DMA, 16B per lane. LDS dest must be wave-uniform base;
// HW adds lane*16.
__device__ __forceinline__ void gld16(const void* g, const void* l)
{
    __builtin_amdgcn_global_load_lds(
        (const __attribute__((address_space(1))) unsigned int*)(unsigned long long)g,
        (__attribute__((address_space(3))) unsigned int*)(unsigned int)(unsigned long long)l,
        16, 0, 0);
}

// ---------------------------------------------------------------------------
// Fused fp32 -> bf16 conversion of all 12 tensors in one launch.
// R8 (verified): LN1 fused for segments 0-3 (the x tensor).
// ---------------------------------------------------------------------------
struct CvtSrcs { const float* p[24]; };

__global__ __launch_bounds__(256) void cvt_all(
    CvtSrcs s, bf16* __restrict__ dst,
    const float* __restrict__ lg, const float* __restrict__ lb,
    bf16* __restrict__ lnout)
{
    const int t = threadIdx.x;
    const int i = (blockIdx.x * 256 + t) * 8;
    const int seg = i >> 20;
    const float* sp = s.p[seg] + (i & 1048575);
    const float4 a = *(const float4*)(sp);
    const float4 b = *(const float4*)(sp + 4);
    const float v[8] = {a.x, a.y, a.z, a.w, b.x, b.y, b.z, b.w};
    bf16 tmp[8];
#pragma unroll
    for (int j = 0; j < 8; ++j) tmp[j] = __float2bfloat16(v[j]);
    *(uint4*)(dst + i) = *(const uint4*)tmp;

    if (seg < 4) {   // x tensor: fused LayerNorm (seg uniform per block)
        float s1 = 0.f, s2 = 0.f;
#pragma unroll
        for (int j = 0; j < 8; ++j) { s1 += v[j]; s2 += v[j] * v[j]; }
#pragma unroll
        for (int off = 32; off > 0; off >>= 1) {
            s1 += __shfl_xor(s1, off, 64);
            s2 += __shfl_xor(s2, off, 64);
        }
        __shared__ float r1[4], r2[4];
        const int w = t >> 6;
        if ((t & 63) == 0) { r1[w] = s1; r2[w] = s2; }
        __syncthreads();
        const int rw = (w >> 1) * 2;        // first wave of this row
        s1 = r1[rw] + r1[rw + 1];
        s2 = r2[rw] + r2[rw + 1];
        const float mean = s1 * (1.f / 1024.f);
        const float var  = s2 * (1.f / 1024.f) - mean * mean;
        const float rstd = rsqrtf(var + 1e-5f);
        bf16 lt[8];
        const int c0 = i & 1023;
#pragma unroll
        for (int j = 0; j < 8; ++j)
            lt[j] = __float2bfloat16((v[j] - mean) * rstd * lg[c0 + j] + lb[c0 + j]);
        *(uint4*)(lnout + i) = *(const uint4*)lt;
    }
}

enum {
    EPI_QSCALE = 0,          // out_bf16 = (C + bias) * 0.125
    EPI_KV = 1,              // N=2048 fused: K plain / Vt transposed
    EPI_RELU = 2,            // out_bf16 = relu(C + bias)
    EPI_RES_F32_F32OUT = 3,  // out_f32  = res_f32 + C + bias
    EPI_PART = 4             // (unused since R8)
};

// ---------------------------------------------------------------------------
// gemm256: C[4096,N] = A[4096,K] @ W[N,K]^T (+bias). 256x256 tile, BK=64,
// 512 thr = 8 waves (2M x 4N), per-wave 128x64 out.
// R10 K-loop (kept: FFN1 left top-5 after this): m201 8-barrier phase
// discipline with counted certify-before-barrier vmcnt.
// Staging/XOR-swizzle (R2, 0 conflicts) and LDS-bounce epilogue (R5).
// ---------------------------------------------------------------------------
template <int EPI>
__global__ __launch_bounds__(512, 2) void gemm256(
    const bf16* __restrict__ A, const bf16* __restrict__ W,
    const float* __restrict__ bias, void* __restrict__ out,
    int N, int Kiter, int Kstride)
{
    __shared__ __align__(16) unsigned short sA[2][2][128 * 64];  // [slot][half]
    __shared__ __align__(16) unsigned short sB[2][2][128 * 64];

    const int t  = threadIdx.x;          // 0..511
    const int l  = t & 63;
    const int w  = t >> 6;               // 0..7
    const int wv = w * 64;
    const int wr = w >> 2;               // 0..1 : M-half of block
    const int wc = w & 3;                // 0..3 : N-quarter of block
    const int lm = l & 15;
    const int kq = l >> 4;
    const int rx = lm & 7;               // read-side swizzle row bits

    int bx = blockIdx.x;
    // XCD-aware: xcd owns 2 contiguous bm-bands; bm iterates fastest.
    const int xcd = bx & 7;
    const int ib  = bx >> 3;
    const int bm  = xcd * 2 + (ib & 1);
    const int bn  = ib >> 1;

    const bf16* gA = A + (size_t)(bm * 256 + (t >> 3)) * Kstride
                       + ((t & 7) ^ ((t >> 3) & 7)) * 8;
    const bf16* gB = W + (size_t)(bn * 256 + (t >> 3)) * Kstride
                       + ((t & 7) ^ ((t >> 3) & 7)) * 8;

#define SQA(slot, kt, j)                                        \
    gld16(gA + (size_t)((j) * 64) * Kstride + (kt) * 64,        \
          &sA[slot][(j) >> 1][(((j) & 1) * 512 + wv) * 8])
#define SQB(slot, kt, j)                                        \
    gld16(gB + (size_t)((j) * 64) * Kstride + (kt) * 64,        \
          &sB[slot][(j) >> 1][(((j) & 1) * 512 + wv) * 8])

    bf16x8 af[4][2], bg[2][2];

#define READ_AF(s_, mh)                                                     \
    do {                                                                    \
        _Pragma("unroll")                                                   \
        for (int mi = 0; mi < 4; ++mi)                                      \
            _Pragma("unroll")                                               \
            for (int kk = 0; kk < 2; ++kk) {                                \
                const int lr = (mh) * 64 + mi * 16 + lm;                    \
                const int sl = ((kk << 2) | kq) ^ rx;                       \
                af[mi][kk] = __builtin_bit_cast(bf16x8,                     \
                    *(const u16x8*)(&sA[s_][wr][lr * 64 + sl * 8]));        \
            }                                                               \
    } while (0)
#define READ_BG(s_, nh)                                                     \
    do {                                                                    \
        _Pragma("unroll")                                                   \
        for (int ni = 0; ni < 2; ++ni)                                      \
            _Pragma("unroll")                                               \
            for (int kk = 0; kk < 2; ++kk) {                                \
                const int lr = (wc & 1) * 64 + (nh) * 32 + ni * 16 + lm;    \
                const int sl = ((kk << 2) | kq) ^ rx;                       \
                bg[ni][kk] = __builtin_bit_cast(bf16x8,                     \
                    *(const u16x8*)(&sB[s_][wc >> 1][lr * 64 + sl * 8]));   \
            }                                                               \
    } while (0)
#define MFMA_QUAD(mh, nh)                                                   \
    do {                                                                    \
        __builtin_amdgcn_s_setprio(1);                                      \
        _Pragma("unroll")                                                   \
        for (int mi = 0; mi < 4; ++mi)                                      \
            _Pragma("unroll")                                               \
            for (int ni = 0; ni < 2; ++ni)                                  \
                _Pragma("unroll")                                           \
                for (int kk = 0; kk < 2; ++kk)                              \
                    acc[(mh) * 4 + mi][(nh) * 2 + ni] =                     \
                        __builtin_amdgcn_mfma_f32_16x16x32_bf16(            \
                            af[mi][kk], bg[ni][kk],                         \
                            acc[(mh) * 4 + mi][(nh) * 2 + ni], 0, 0, 0);    \
        __builtin_amdgcn_s_setprio(0);                                      \
    } while (0)
#define BARRIER() do { __builtin_amdgcn_s_barrier();                        \
                       __builtin_amdgcn_sched_barrier(0); } while (0)
#define LGKM0() do { asm volatile("s_waitcnt lgkmcnt(0)" ::: "memory");     \
                     __builtin_amdgcn_sched_barrier(0); } while (0)
#define WAITV2() asm volatile("s_waitcnt vmcnt(2)" ::: "memory")
#define WAITV0() asm volatile("s_waitcnt vmcnt(0)" ::: "memory")

    f32x4 acc[8][4] = {};
    const int NT = Kiter >> 6;

    // prologue: tile 0 -> slot 0; issue order b0 b1 b2 b3 a0 a2 a1 a3.
    SQB(0, 0, 0); SQB(0, 0, 1); SQB(0, 0, 2); SQB(0, 0, 3);
    SQA(0, 0, 0); SQA(0, 0, 2); SQA(0, 0, 1); SQA(0, 0, 3);
    WAITV2();
    __syncthreads();

    for (int tt = 0; tt < NT - 1; ++tt) {
        const int s = tt & 1, d = s ^ 1, kn = tt + 1;
        // P0 (mh0,nh0): reads certified; stage b0',b1'; certify a1,a3
        READ_AF(s, 0); READ_BG(s, 0);
        SQB(d, kn, 0); SQB(d, kn, 1);
        WAITV2();                 // 4 outstanding -> completes a1,a3
        BARRIER(); LGKM0();
        MFMA_QUAD(0, 0);
        BARRIER();
        // P1 (mh1,nh0): reads a1,a3 (certified at P0)
        READ_AF(s, 1);
        SQB(d, kn, 2); SQB(d, kn, 3);
        BARRIER(); LGKM0();
        MFMA_QUAD(1, 0);
        BARRIER();
        // P2 (mh1,nh1)
        READ_BG(s, 1);
        SQA(d, kn, 0); SQA(d, kn, 2);
        BARRIER(); LGKM0();
        MFMA_QUAD(1, 1);
        BARRIER();
        // P3 (mh0,nh1): stage a1',a3'; certify next tile's oldest 6
        READ_AF(s, 0);
        SQA(d, kn, 1); SQA(d, kn, 3);
        WAITV2();                 // 8 outstanding -> completes b0'..b3',a0',a2'
        BARRIER(); LGKM0();
        MFMA_QUAD(0, 1);
        BARRIER();
    }
    {   // final tile: 2 outstanding (a1,a3) -> drain at entry; no staging
        const int s = (NT - 1) & 1;
        READ_AF(s, 0); READ_BG(s, 0);
        WAITV0();
        BARRIER(); LGKM0();
        MFMA_QUAD(0, 0);
        BARRIER();
        READ_AF(s, 1);
        MFMA_QUAD(1, 0);
        READ_BG(s, 1);
        MFMA_QUAD(1, 1);
        READ_AF(s, 0);
        MFMA_QUAD(0, 1);
    }

    // ---- Epilogue (R5): LDS-bounce vectorized store ----
    __syncthreads();
    unsigned short* scr = (w < 4) ? &sA[0][0][0] + w * 8192
                                  : &sB[0][0][0] + (w - 4) * 8192;

#pragma unroll
    for (int NI = 0; NI < 4; ++NI) {
        const int col = bn * 256 + wc * 64 + NI * 16 + lm;
        const float bv = bias[col];
        const int c  = NI * 2 + (lm >> 3);
        const int ci = lm & 7;
#pragma unroll
        for (int MI = 0; MI < 8; ++MI) {
#pragma unroll
            for (int r = 0; r < 4; ++r) {
                float v = acc[MI][NI][r] + bv;
                if (EPI == EPI_RELU) v = fmaxf(v, 0.f);
                const int row = MI * 16 + kq * 4 + r;
                scr[row * 64 + ((c ^ (row & 7)) * 8) + ci] =
                    __builtin_bit_cast(unsigned short, (__bf16)v);
            }
        }
    }
#pragma unroll
    for (int it = 0; it < 16; ++it) {
        const int row = it * 8 + (l >> 3);
        const int lc  = l & 7;
        const u16x8 vv = *(const u16x8*)&scr[row * 64 + ((lc ^ (row & 7)) * 8)];
        const int Crow = bm * 256 + wr * 128 + row;
        const int Ccol = bn * 256 + wc * 64 + lc * 8;
        *(u16x8*)((bf16*)out + (size_t)Crow * N + Ccol) = vv;
    }
#undef SQA
#undef SQB
#undef READ_AF
#undef READ_BG
#undef MFMA_QUAD
#undef BARRIER
#undef LGKM0
#undef WAITV2
#undef WAITV0
}

// ---------------------------------------------------------------------------
// gemm_bt body: 128x64 tile, BK=64, 4 waves (2M x 2N), wave-tile 64x32,
// LDS 48KB, up to 3 blocks/CU (grid-limited to 2 at 512 blocks).
// R12 K-loop: deep-cover single-wait schedule. ALL 6 stages for tile tt+1
// are issued at tile tt entry (right after the barrier), so every load has
// a FULL TILE of phases (~600-1200 cy) of latency cover (R9's spread-stage
// gave only ~300 cy vs 200-900 cy L2/HBM latency -> unhidden waits were
// ~90% of FFN2's time). One vmcnt(0)+barrier per tile: at entry the only
// outstanding loads are tile tt's own (issued one full tile earlier), so
// the drain is near-free. WAR safe: all slot reads are consumed by MFMAs
// (compiler lgkmcnt) before the entry barrier; writes to the other slot
// occur only after it.
// ---------------------------------------------------------------------------
template <int EPI>
__device__ __forceinline__ void gemm_bt_body(
    unsigned short* __restrict__ sAp, unsigned short* __restrict__ sBp,
    const bf16* __restrict__ A, const bf16* __restrict__ W,
    const float* __restrict__ bias, const float* __restrict__ bias2,
    const float* __restrict__ res, void* __restrict__ out,
    int N, int Kiter, int Kstride, int bx)
{
    const int t  = threadIdx.x;     // 0..255
    const int l  = t & 63;
    const int w  = t >> 6;          // 0..3
    const int wv = w * 64;
    const int wr = w >> 1;          // 0..1 : M-half (64 rows)
    const int wc = w & 1;           // 0..1 : N-half (32 cols)
    const int lm = l & 15;
    const int kq = l >> 4;
    const int rx = lm & 7;

    const int xcd = bx & 7;
    const int ib  = bx >> 3;
    const int bm  = xcd * 4 + (ib & 3);   // 32 bm tiles, 4 per XCD
    const int bn  = ib >> 2;

    const bf16* gA = A + (size_t)(bm * 128 + (t >> 3)) * Kstride
                       + ((t & 7) ^ ((t >> 3) & 7)) * 8;
    const bf16* gB = W + (size_t)(bn * 64 + (t >> 3)) * Kstride
                       + ((t & 7) ^ ((t >> 3) & 7)) * 8;

#define SQA_B(slot, kt, j)                                      \
    gld16(gA + (size_t)((j) * 32) * Kstride + (kt) * 64,        \
          sAp + (slot) * 8192 + ((j) * 256 + wv) * 8)
#define SQB_B(slot, kt, j)                                      \
    gld16(gB + (size_t)((j) * 32) * Kstride + (kt) * 64,        \
          sBp + (slot) * 4096 + ((j) * 256 + wv) * 8)

    bf16x8 af[4][2], bg[2][2];

#define READ_A_B(s_, mh, kk)                                                \
    do {                                                                    \
        _Pragma("unroll")                                                   \
        for (int m2 = 0; m2 < 2; ++m2) {                                    \
            const int mi = (mh) * 2 + m2;                                   \
            const int lr = wr * 64 + mi * 16 + lm;                          \
            const int sl = (((kk) << 2) | kq) ^ rx;                         \
            af[mi][kk] = __builtin_bit_cast(bf16x8,                         \
                *(const u16x8*)(sAp + (s_) * 8192 + lr * 64 + sl * 8));     \
        }                                                                   \
    } while (0)
#define READ_B_B(s_, kk)                                                    \
    do {                                                                    \
        _Pragma("unroll")                                                   \
        for (int ni = 0; ni < 2; ++ni) {                                    \
            const int lr = wc * 32 + ni * 16 + lm;                          \
            const int sl = (((kk) << 2) | kq) ^ rx;                         \
            bg[ni][kk] = __builtin_bit_cast(bf16x8,                         \
                *(const u16x8*)(sBp + (s_) * 4096 + lr * 64 + sl * 8));     \
        }                                                                   \
    } while (0)
#define MFMA_PH_B(mh, kk)                                                   \
    do {                                                                    \
        __builtin_amdgcn_s_setprio(1);                                      \
        _Pragma("unroll")                                                   \
        for (int m2 = 0; m2 < 2; ++m2)                                      \
            _Pragma("unroll")                                               \
            for (int ni = 0; ni < 2; ++ni)                                  \
                acc[(mh) * 2 + m2][ni] =                                    \
                    __builtin_amdgcn_mfma_f32_16x16x32_bf16(                \
                        af[(mh) * 2 + m2][kk], bg[ni][kk],                  \
                        acc[(mh) * 2 + m2][ni], 0, 0, 0);                   \
        __builtin_amdgcn_s_setprio(0);                                      \
    } while (0)
#define BARRIER_B() do { __builtin_amdgcn_s_barrier();                      \
                         __builtin_amdgcn_sched_barrier(0); } while (0)
#define WAITV0_B() asm volatile("s_waitcnt vmcnt(0)" ::: "memory")

    f32x4 acc[4][2] = {};
    const int NT = Kiter >> 6;

    // prologue: stage all 6 of tile 0 into slot 0
    SQB_B(0, 0, 0); SQB_B(0, 0, 1);
    SQA_B(0, 0, 0); SQA_B(0, 0, 1); SQA_B(0, 0, 2); SQA_B(0, 0, 3);

    for (int tt = 0; tt < NT; ++tt) {
        const int s = tt & 1, d = s ^ 1, kn = tt + 1;
        // Entry: drain tile tt's 6 loads (issued one full tile ago) and
        // publish; then immediately issue ALL of tile tt+1 -> full-tile cover.
        WAITV0_B(); BARRIER_B();
        if (kn < NT) {
            SQB_B(d, kn, 0); SQB_B(d, kn, 1);
            SQA_B(d, kn, 0); SQA_B(d, kn, 1); SQA_B(d, kn, 2); SQA_B(d, kn, 3);
        }
        // Phases: reads of slot s all certified by the entry wait+barrier.
        READ_A_B(s, 0, 0); READ_B_B(s, 0);
        MFMA_PH_B(0, 0);
        READ_A_B(s, 1, 0);
        MFMA_PH_B(1, 0);
        READ_A_B(s, 1, 1); READ_B_B(s, 1);
        MFMA_PH_B(1, 1);
        READ_A_B(s, 0, 1);
        MFMA_PH_B(0, 1);
    }
#undef SQA_B
#undef SQB_B
#undef READ_A_B
#undef READ_B_B
#undef MFMA_PH_B
#undef BARRIER_B
#undef WAITV0_B

    // Epilogue. C/D: col = lane&15 (+16*ni), row = kq*4 + r (+16*mi).
#pragma unroll
    for (int ni = 0; ni < 2; ++ni) {
        const int col = bn * 64 + wc * 32 + ni * 16 + lm;
        float bv = 0.f;
        if (EPI == EPI_KV) bv = (col < 1024) ? bias[col] : bias2[col - 1024];
        else bv = bias[col];
#pragma unroll
        for (int mi = 0; mi < 4; ++mi) {
#pragma unroll
            for (int r = 0; r < 4; ++r) {
                const int row = bm * 128 + wr * 64 + mi * 16 + kq * 4 + r;
                float v = acc[mi][ni][r] + bv;
                if (EPI == EPI_QSCALE) v *= 0.125f;
                if (EPI == EPI_RELU) v = fmaxf(v, 0.f);
                if (EPI == EPI_KV) {
                    if (col < 1024) {
                        ((bf16*)out)[(size_t)row * 1024 + col] = __float2bfloat16(v);
                    } else {
                        const int ch = col - 1024;  // h*64 + d
                        const size_t idx = (size_t)4 * 1048576 +
                            ((size_t)((row >> 10) * 16 + (ch >> 6)) * 64 + (ch & 63)) * 1024
                            + (row & 1023);
                        ((bf16*)out)[idx] = __float2bfloat16(v);
                    }
                } else if (EPI == EPI_RES_F32_F32OUT) {
                    const size_t idx = (size_t)row * N + col;
                    ((float*)out)[idx] = v + res[idx];
                } else {
                    ((bf16*)out)[(size_t)row * N + col] = __float2bfloat16(v);
                }
            }
        }
    }
}

template <int EPI>
__global__ __launch_bounds__(256, 3) void gemm_bt(
    const bf16* __restrict__ A, const bf16* __restrict__ W,
    const float* __restrict__ bias, const float* __restrict__ bias2,
    const float* __restrict__ res, void* __restrict__ out,
    int M, int N, int Kiter, int Kstride)
{
    __shared__ __align__(16) unsigned short sA[2 * 128 * 64];
    __shared__ __align__(16) unsigned short sB[2 * 64 * 64];
    gemm_bt_body<EPI>(sA, sB, A, W, bias, bias2, res, out,
                      N, Kiter, Kstride, blockIdx.x);
}

// ---------------------------------------------------------------------------
// qkv_fused (R10): QSCALE (512 blocks) + KV (1024 blocks) in one 1536-block
// launch. Block-range dispatch; local bx keeps XCD swizzle parity.
// ---------------------------------------------------------------------------
__global__ __launch_bounds__(256, 3) void qkv_fused(
    const bf16* __restrict__ Aq, const bf16* __restrict__ Wq,
    const float* __restrict__ bq, bf16* __restrict__ Qb,
    const bf16* __restrict__ Akv, const bf16* __restrict__ Wkv,
    const float* __restrict__ bk, const float* __restrict__ bv,
    bf16* __restrict__ Kb)
{
    __shared__ __align__(16) unsigned short sA[2 * 128 * 64];
    __shared__ __align__(16) unsigned short sB[2 * 64 * 64];
    const int bx = blockIdx.x;
    if (bx < 512)
        gemm_bt_body<EPI_QSCALE>(sA, sB, Aq, Wq, bq, nullptr, nullptr, Qb,
                                 1024, 1024, 1024, bx);
    else
        gemm_bt_body<EPI_KV>(sA, sB, Akv, Wkv, bk, bv, nullptr, Kb,
                             2048, 1024, 1024, bx - 512);
}

// ---------------------------------------------------------------------------
// Flash attention (MFMA). R6a/R6b verified: XCD-local remap + swizzled
// conflict-free K/V tiles.
// ---------------------------------------------------------------------------
template <bool CAUSAL, bool SBIAS>
__global__ __launch_bounds__(256, 2) void flash_attn(
    const bf16* __restrict__ Q, const bf16* __restrict__ K,
    const bf16* __restrict__ Vt, bf16* __restrict__ O,
    const float* __restrict__ sbias, const float* __restrict__ scale_ptr)
{
    __shared__ __align__(16) unsigned short sK[2][64 * 64];
    __shared__ __align__(16) unsigned short sV[2][64 * 64];
    __shared__ __align__(16) unsigned short sP[4 * 32 * 72];

    const int t  = threadIdx.x;
    const int l  = t & 63;
    const int w  = t >> 6;
    const int wv = w * 64;
    const int lm = l & 15;
    const int kq = l >> 4;

    const int bh = blockIdx.x & 63;      // same-XCD for all 8 q-blocks of bh
    const int qb = blockIdx.x >> 6;
    const int h  = bh & 15;
    const int b  = bh >> 4;

    const int tb = qb * 128 + w * 32;
    const size_t qrow0 = (size_t)(b * 1024 + tb) * 1024 + h * 64;

    bf16x8 qf[2][2];
#pragma unroll
    for (int mi = 0; mi < 2; ++mi)
#pragma unroll
        for (int kk = 0; kk < 2; ++kk)
            qf[mi][kk] = __builtin_bit_cast(bf16x8,
                *(const u16x8*)(Q + qrow0 + (size_t)(mi * 16 + lm) * 1024 + kk * 32 + kq * 8));

    float cs = 0.f; const float* sb = nullptr;
    if (SBIAS) { cs = scale_ptr[0]; sb = sbias + b * 1024; }

    const bf16* gK = K  + (size_t)(b * 1024 + (t >> 3)) * 1024 + h * 64
                   + ((t & 7) ^ ((t >> 3) & 7)) * 8;
    const bf16* gV = Vt + (size_t)((b * 16 + h) * 64 + (t >> 3)) * 1024
                   + ((t & 7) ^ ((t >> 3) & 7)) * 8;
    __bf16* sPw = (__bf16*)sP + w * 32 * 72;

#define STAGE_KV(buf, s0r)                                                   \
    do {                                                                     \
        gld16(gK + (size_t)(s0r) * 1024,        &sK[buf][wv * 8]);           \
        gld16(gK + (size_t)((s0r) + 32) * 1024, &sK[buf][2048 + wv * 8]);    \
        gld16(gV + (s0r),                       &sV[buf][wv * 8]);           \
        gld16(gV + (s0r) + 32 * 1024,           &sV[buf][2048 + wv * 8]);    \
    } while (0)

    const int niter = CAUSAL ? (2 * qb + 2) : 16;

    STAGE_KV(0, 0);
    __syncthreads();

    f32x4 acc_o[2][4] = {};
    f32x4 l_run[2] = {};

    for (int it = 0; it < niter; ++it) {
        const int s0 = it * 64;
        const int cur = it & 1;

        if (it + 1 < niter) STAGE_KV(cur ^ 1, s0 + 64);

        f32x4 accs[2][4] = {};
#pragma unroll
        for (int ni = 0; ni < 4; ++ni)
#pragma unroll
            for (int kk = 0; kk < 2; ++kk) {
                const bf16x8 kf = __builtin_bit_cast(bf16x8,
                    *(const u16x8*)(&sK[cur][(ni * 16 + lm) * 64
                        + ((((kk << 2) | kq)) ^ (lm & 7)) * 8]));
#pragma unroll
                for (int mi = 0; mi < 2; ++mi)
                    accs[mi][ni] = __builtin_amdgcn_mfma_f32_16x16x32_bf16(
                        qf[mi][kk], kf, accs[mi][ni], 0, 0, 0);
            }

        if (SBIAS) {
#pragma unroll
            for (int ni = 0; ni < 4; ++ni) {
                const float sv = cs * sb[s0 + ni * 16 + lm];
#pragma unroll
                for (int mi = 0; mi < 2; ++mi)
#pragma unroll
                    for (int r = 0; r < 4; ++r) accs[mi][ni][r] += sv;
            }
        }
        if (CAUSAL && (s0 + 63 > tb)) {
#pragma unroll
            for (int ni = 0; ni < 4; ++ni) {
                const int s = s0 + ni * 16 + lm;
#pragma unroll
                for (int mi = 0; mi < 2; ++mi)
#pragma unroll
                    for (int r = 0; r < 4; ++r)
                        if (s > tb + mi * 16 + kq * 4 + r) accs[mi][ni][r] = -1e30f;
            }
        }

#pragma unroll
        for (int mi = 0; mi < 2; ++mi)
#pragma unroll
            for (int ni = 0; ni < 4; ++ni)
#pragma unroll
                for (int r = 0; r < 4; ++r) {
                    const float e = __expf(accs[mi][ni][r]);
                    l_run[mi][r] += e;
                    sPw[(mi * 16 + kq * 4 + r) * 72 + ni * 16 + lm] = (__bf16)e;
                }

#pragma unroll
        for (int kk = 0; kk < 2; ++kk) {
            bf16x8 pf[2];
#pragma unroll
            for (int mi = 0; mi < 2; ++mi)
                pf[mi] = __builtin_bit_cast(bf16x8,
                    *(const u16x8*)(sPw + (mi * 16 + lm) * 72 + kk * 32 + kq * 8));
#pragma unroll
            for (int di = 0; di < 4; ++di) {
                const bf16x8 vf = __builtin_bit_cast(bf16x8,
                    *(const u16x8*)(&sV[cur][(di * 16 + lm) * 64
                        + ((((kk << 2) | kq)) ^ (lm & 7)) * 8]));
#pragma unroll
                for (int mi = 0; mi < 2; ++mi)
                    acc_o[mi][di] = __builtin_amdgcn_mfma_f32_16x16x32_bf16(
                        pf[mi], vf, acc_o[mi][di], 0, 0, 0);
            }
        }

        __syncthreads();
    }
#undef STAGE_KV

#pragma unroll
    for (int mi = 0; mi < 2; ++mi) {
        f32x4 lt = l_run[mi];
#pragma unroll
        for (int x = 1; x < 16; x <<= 1)
#pragma unroll
            for (int r = 0; r < 4; ++r) lt[r] += __shfl_xor(lt[r], x, 64);
#pragma unroll
        for (int r = 0; r < 4; ++r) lt[r] = 1.f / lt[r];
#pragma unroll
        for (int di = 0; di < 4; ++di)
#pragma unroll
            for (int r = 0; r < 4; ++r) {
                const size_t idx = (size_t)(b * 1024 + tb + mi * 16 + kq * 4 + r) * 1024
                                 + h * 64 + di * 16 + lm;
                O[idx] = __float2bfloat16(acc_o[mi][di][r] * lt[r]);
            }
    }
}

// ---------------------------------------------------------------------------
// LayerNorm over D=1024 (fp32 in, bf16 out), one block per row, 4 elems/thr.
// ---------------------------------------------------------------------------
__global__ __launch_bounds__(256) void ln_kernel(
    const float* __restrict__ xin, const float* __restrict__ g,
    const float* __restrict__ bta, bf16* __restrict__ out)
{
    const int row = blockIdx.x;
    const int t = threadIdx.x;
    const size_t base = (size_t)row * 1024 + t * 4;

    const float4 f = *(const float4*)(xin + base);
    const float v[4] = {f.x, f.y, f.z, f.w};
    float s1 = v[0] + v[1] + v[2] + v[3];
    float s2 = v[0]*v[0] + v[1]*v[1] + v[2]*v[2] + v[3]*v[3];
#pragma unroll
    for (int off = 32; off > 0; off >>= 1) {
        s1 += __shfl_xor(s1, off, 64);
        s2 += __shfl_xor(s2, off, 64);
    }
    __shared__ float r1[4], r2[4];
    if ((t & 63) == 0) { r1[t >> 6] = s1; r2[t >> 6] = s2; }
    __syncthreads();
    s1 = r1[0] + r1[1] + r1[2] + r1[3];
    s2 = r2[0] + r2[1] + r2[2] + r2[3];
    const float mean = s1 * (1.f / 1024.f);
    const float var  = s2 * (1.f / 1024.f) - mean * mean;
    const float rstd = rsqrtf(var + 1e-5f);
#pragma unroll
    for (int j = 0; j < 4; ++j) {
        const int c = t * 4 + j;
        out[base + j] = __float2bfloat16((v[j] - mean) * rstd * g[c] + bta[c]);
    }
}

// ---------------------------------------------------------------------------
extern "C" void kernel_launch(void* const* d_in, const int* in_sizes, int n_in,
                              void* d_out, int out_size, void* d_ws, size_t ws_size,
                              hipStream_t stream)
{
    const float* x       = (const float*)d_in[0];
    const float* memory  = (const float*)d_in[1];
    const float* sbias   = (const float*)d_in[2];
    const float* sa_bq = (const float*)d_in[7];
    const float* sa_bk = (const float*)d_in[9];
    const float* sa_bv = (const float*)d_in[11];
    const float* sa_bo = (const float*)d_in[13];
    const float* ca_bq = (const float*)d_in[16];
    const float* ca_bk = (const float*)d_in[18];
    const float* ca_bv = (const float*)d_in[20];
    const float* ca_bo = (const float*)d_in[22];
    const float* ca_scale = (const float*)d_in[23];
    const float* ln1_g = (const float*)d_in[24]; const float* ln1_b = (const float*)d_in[25];
    const float* ln2_g = (const float*)d_in[26]; const float* ln2_b = (const float*)d_in[27];
    const float* ln3_g = (const float*)d_in[28]; const float* ln3_b = (const float*)d_in[29];
    const float* b1 = (const float*)d_in[31];
    const float* b2 = (const float*)d_in[33];

    char* ws = (char*)d_ws;
    const size_t MB = (size_t)1 << 20;
    float* x1    = (float*)(ws + 0 * MB);
    float* x2    = (float*)(ws + 16 * MB);
    bf16* lnbuf  = (bf16*)(ws + 32 * MB);
    bf16* Qb     = (bf16*)(ws + 40 * MB);
    bf16* Kb     = (bf16*)(ws + 48 * MB);
    bf16* Vtb    = (bf16*)(ws + 56 * MB);
    bf16* Ob     = (bf16*)(ws + 64 * MB);
    bf16* ffnmid = (bf16*)(ws + 40 * MB);
    bf16* wx     = (bf16*)(ws + 72 * MB);
    bf16* wmem   = (bf16*)(ws + 80 * MB);
    bf16* bw     = (bf16*)(ws + 88 * MB);
    bf16* b_sa_wq = bw + 0 * 1048576, *b_sa_wk = bw + 1 * 1048576;
    bf16* b_sa_wo = bw + 3 * 1048576;
    bf16* b_ca_wq = bw + 4 * 1048576, *b_ca_wk = bw + 5 * 1048576;
    bf16* b_ca_wo = bw + 7 * 1048576;
    bf16* b_w1   = (bf16*)(ws + 104 * MB);
    bf16* b_w2   = (bf16*)(ws + 112 * MB);

    const int M = 4096;
    dim3 blk256(256), blk512(512);
    const dim3 gQ(512);      // (4096/128)*(1024/64): 128x64 tiles
    const dim3 gQKV(1536);   // fused: 512 QSCALE + 1024 KV
    const dim3 gFA(512);     // 64 (b,h) x 8 q-blocks
    const dim3 g256(256);    // FFN1: 16x16 tiles (256^2)

    CvtSrcs cs;
    for (int c = 0; c < 4; ++c) {
        cs.p[c]      = x + (size_t)c * 1048576;
        cs.p[4 + c]  = memory + (size_t)c * 1048576;
        cs.p[16 + c] = (const float*)d_in[30] + (size_t)c * 1048576;  // w1
        cs.p[20 + c] = (const float*)d_in[32] + (size_t)c * 1048576;  // w2
    }
    cs.p[8]  = (const float*)d_in[6];
    cs.p[9]  = (const float*)d_in[8];
    cs.p[10] = (const float*)d_in[10];
    cs.p[11] = (const float*)d_in[12];
    cs.p[12] = (const float*)d_in[15];
    cs.p[13] = (const float*)d_in[17];
    cs.p[14] = (const float*)d_in[19];
    cs.p[15] = (const float*)d_in[21];
    // cvt + fused LN1 (segments 0-3 = x -> lnbuf)
    cvt_all<<<24 * 1048576 / 2048, blk256, 0, stream>>>(
        cs, wx, ln1_g, ln1_b, lnbuf);

    // ---- self-attention ----
    qkv_fused<<<gQKV, blk256, 0, stream>>>(
        lnbuf, b_sa_wq, sa_bq, Qb, wx, b_sa_wk, sa_bk, sa_bv, Kb);
    flash_attn<true, false><<<gFA, blk256, 0, stream>>>(Qb, Kb, Vtb, Ob, nullptr, nullptr);
    gemm_bt<EPI_RES_F32_F32OUT><<<gQ, blk256, 0, stream>>>(
        Ob, b_sa_wo, sa_bo, nullptr, x, x1, M, 1024, 1024, 1024);

    // ---- cross-attention ----
    ln_kernel<<<4096, blk256, 0, stream>>>(x1, ln2_g, ln2_b, lnbuf);
    qkv_fused<<<gQKV, blk256, 0, stream>>>(
        lnbuf, b_ca_wq, ca_bq, Qb, wmem, b_ca_wk, ca_bk, ca_bv, Kb);
    flash_attn<false, true><<<gFA, blk256, 0, stream>>>(Qb, Kb, Vtb, Ob, sbias, ca_scale);
    gemm_bt<EPI_RES_F32_F32OUT><<<gQ, blk256, 0, stream>>>(
        Ob, b_ca_wo, ca_bo, nullptr, x1, x2, M, 1024, 1024, 1024);

    // ---- FFN ----
    ln_kernel<<<4096, blk256, 0, stream>>>(x2, ln3_g, ln3_b, lnbuf);
    gemm256<EPI_RELU><<<g256, blk512, 0, stream>>>(
        lnbuf, b_w1, b1, ffnmid, 4096, 1024, 1024);
    // FFN2 direct (R8): K=4096, fused residual + bias, fp32 out.
    gemm_bt<EPI_RES_F32_F32OUT><<<gQ, blk256, 0, stream>>>(
        ffnmid, b_w2, b2, nullptr, x2, d_out, M, 1024, 4096, 4096);
}